// Round 1
// baseline (1070.648 us; speedup 1.0000x reference)
//
#include <hip/hip_runtime.h>

// cheb_conv_aagcn: B=8,K=3,N=2048,F_IN=16,F_OUT=64,T=12
// d_in: [0]=x (B,N,16,12) f32, [1]=spatial_attention (B,3,N,N) f32,
//       [2]=adj (N,N) f32, [3]=Theta (3,16,64) f32
// out: (B,N,64,12) f32
//
// Pipeline:
//  k_deg : deg[n] = sum_j adj[n][j]
//  k_xt  : xT[b][ft][m] = bf16(x[b][m][ft])   (pre-transpose for MFMA B-frags)
//  k_main: per (b,k,n-tile of 64): fused exp/cheb/Z + bf16 MFMA over m
//          k==0 path: only Z and diagonal -> coef0[b][n]
//          k==1,2: rhs[bk][n][ft] = (1/Z[n]) * sum_m exp(s)*cheb_k * x
//  k_out : out = relu(coef0*x@Th0 + rhs1@Th1 + rhs2@Th2)

#define NB 8
#define NK 3
#define NN 2048
#define FT 192
#define BN 64
#define BM 64
#define LBM 72  // LDS row stride in bf16: 144B, 16B-aligned

typedef __attribute__((ext_vector_type(8))) short short8;
typedef __attribute__((ext_vector_type(4))) float f32x4;

__device__ __forceinline__ unsigned short bf16_rne(float f) {
  unsigned u = __float_as_uint(f);
  u += 0x7FFFu + ((u >> 16) & 1u);
  return (unsigned short)(u >> 16);
}

__global__ __launch_bounds__(256) void k_deg(const float* __restrict__ adj,
                                             float* __restrict__ deg) {
  const int row = blockIdx.x;
  const float* r = adj + (size_t)row * NN;
  float s = 0.f;
  for (int j = threadIdx.x; j < NN; j += 256) s += r[j];
  for (int off = 32; off; off >>= 1) s += __shfl_down(s, off, 64);
  __shared__ float ls[4];
  if ((threadIdx.x & 63) == 0) ls[threadIdx.x >> 6] = s;
  __syncthreads();
  if (threadIdx.x == 0) deg[row] = ls[0] + ls[1] + ls[2] + ls[3];
}

// block 256 thr, grid (32, 8): transpose+convert x[b][m][ft] -> xT[b][ft][m] bf16
__global__ __launch_bounds__(256) void k_xt(const float* __restrict__ x,
                                            unsigned short* __restrict__ xT) {
  __shared__ unsigned short tile[FT][66];
  const int b = blockIdx.y, m0 = blockIdx.x * 64;
  const float* src = x + ((size_t)b * NN + m0) * FT;
#pragma unroll
  for (int p = 0; p < 48; ++p) {
    const int idx = threadIdx.x + p * 256;  // 0..12287
    const int ml = idx / FT, ft = idx % FT;
    tile[ft][ml] = bf16_rne(src[idx]);
  }
  __syncthreads();
  unsigned* dst = (unsigned*)xT;
#pragma unroll
  for (int p = 0; p < 24; ++p) {
    const int idx = threadIdx.x + p * 256;  // 0..6143
    const int ft = idx / 32, c = idx % 32;
    unsigned v = (unsigned)tile[ft][2 * c] | ((unsigned)tile[ft][2 * c + 1] << 16);
    dst[((size_t)b * FT + ft) * (NN / 2) + m0 / 2 + c] = v;
  }
}

// block 192 thr (3 waves), grid (32, 3, 8): x=n-tile, y=k, z=b
__global__ __launch_bounds__(192, 2) void k_main(
    const float* __restrict__ Sall, const float* __restrict__ adj,
    const float* __restrict__ deg, const unsigned short* __restrict__ xT,
    float* __restrict__ coef0, float* __restrict__ rhs) {
  __shared__ unsigned short Pt[BN * LBM];   // P^T[n][m] bf16
  __shared__ unsigned short Xt[FT * LBM];   // X^T[ft][m] bf16
  __shared__ float Zred[8][BN];
  __shared__ float rcpZ[BN];

  const int tile = blockIdx.x, k = blockIdx.y, b = blockIdx.z;
  const int n0 = tile * BN;
  const int t = threadIdx.x;
  const float* S = Sall + (size_t)(b * NK + k) * NN * NN;

  if (k == 0) {
    // cheb0 = I: only need Z[n] and diag exp -> coef0 = exp(s[n,n])/Z
    const int n = t & 63, mg = t >> 6;  // mg in 0..2
    float z = 0.f, d = 0.f;
    for (int m = mg; m < NN; m += 3) {
      float e = __expf(S[(size_t)m * NN + n0 + n]);
      z += e;
      if (m == n0 + n) d = e;
    }
    Zred[mg][n] = z;
    Zred[4 + mg][n] = d;
    __syncthreads();
    if (t < 64) {
      float Z = Zred[0][t] + Zred[1][t] + Zred[2][t];
      float D = Zred[4][t] + Zred[5][t] + Zred[6][t];
      coef0[b * NN + n0 + t] = D / Z;
    }
    return;
  }

  const bool isK1 = (k == 1);
  const f32x4 zero4 = {0.f, 0.f, 0.f, 0.f};
  f32x4 acc[4][4];
#pragma unroll
  for (int i = 0; i < 4; ++i)
#pragma unroll
    for (int q = 0; q < 4; ++q) acc[i][q] = zero4;

  float zp[4] = {0.f, 0.f, 0.f, 0.f};
  const int lane = t & 63, w = t >> 6;
  const int ln = lane & 15, quad = lane >> 4;
  const int n4 = (t & 15) * 4;   // Pt staging: 4 n's per thread
  const int mg = (t >> 4) & 7;   // Pt staging: m-group (8 m's)
  const bool doPt = (t < 128);   // waves 0,1 stage Pt; wave 2 copies Xt

  for (int c = 0; c < 32; ++c) {
    const int m0 = c * BM;
    if (doPt) {
      const int mb = m0 + mg * 8;
#pragma unroll
      for (int g = 0; g < 2; ++g) {
        float4 sv[4], av[4];
        float dg[4];
#pragma unroll
        for (int i = 0; i < 4; ++i) {
          const size_t ro = (size_t)(mb + g * 4 + i) * NN + n0 + n4;
          sv[i] = *(const float4*)(S + ro);
          av[i] = *(const float4*)(adj + ro);
          dg[i] = deg[mb + g * 4 + i];
        }
        unsigned short pk[4][4];
#pragma unroll
        for (int i = 0; i < 4; ++i) {
          const int m = mb + g * 4 + i;
          const float se[4] = {sv[i].x, sv[i].y, sv[i].z, sv[i].w};
          const float ae[4] = {av[i].x, av[i].y, av[i].z, av[i].w};
#pragma unroll
          for (int j = 0; j < 4; ++j) {
            const bool diag = (m == n0 + n4 + j);
            const float e = __expf(se[j]);
            zp[j] += e;
            const float L = (diag ? dg[i] : 0.f) - ae[j];
            const float cc = isK1 ? L : (2.f * L * L - (diag ? 1.f : 0.f));
            pk[i][j] = bf16_rne(e * cc);
          }
        }
#pragma unroll
        for (int j = 0; j < 4; ++j) {
          uint2 v;
          v.x = (unsigned)pk[0][j] | ((unsigned)pk[1][j] << 16);
          v.y = (unsigned)pk[2][j] | ((unsigned)pk[3][j] << 16);
          *(uint2*)&Pt[(n4 + j) * LBM + mg * 8 + g * 4] = v;
        }
      }
    } else {
      const unsigned short* xp = xT + (size_t)b * FT * NN + m0;
      const int l = t - 128;
#pragma unroll
      for (int p = 0; p < 24; ++p) {
        const int idx = l + p * 64;          // 0..1535
        const int row = idx >> 3, col = idx & 7;
        uint4 v = *(const uint4*)(xp + (size_t)row * NN + col * 8);
        *(uint4*)&Xt[row * LBM + col * 8] = v;
      }
    }
    __syncthreads();
#pragma unroll
    for (int ks = 0; ks < 2; ++ks) {
      const int moff = ks * 32 + quad * 8;
      short8 af[4], bfr[4];
#pragma unroll
      for (int i = 0; i < 4; ++i)
        af[i] = *(const short8*)&Pt[(i * 16 + ln) * LBM + moff];
#pragma unroll
      for (int q = 0; q < 4; ++q)
        bfr[q] = *(const short8*)&Xt[((w * 4 + q) * 16 + ln) * LBM + moff];
#pragma unroll
      for (int i = 0; i < 4; ++i)
#pragma unroll
        for (int q = 0; q < 4; ++q)
          acc[i][q] = __builtin_amdgcn_mfma_f32_16x16x32_bf16(af[i], bfr[q],
                                                              acc[i][q], 0, 0, 0);
    }
    __syncthreads();
  }

  if (doPt) {
#pragma unroll
    for (int j = 0; j < 4; ++j) Zred[mg][n4 + j] = zp[j];
  }
  __syncthreads();
  if (t < 64) {
    float Z = 0.f;
#pragma unroll
    for (int g = 0; g < 8; ++g) Z += Zred[g][t];
    rcpZ[t] = 1.f / Z;
  }
  __syncthreads();

  float* outp = rhs + ((size_t)((b * 2 + (k - 1)) * NN) + n0) * FT;
#pragma unroll
  for (int i = 0; i < 4; ++i) {
#pragma unroll
    for (int q = 0; q < 4; ++q) {
      const int ft = (w * 4 + q) * 16 + ln;
#pragma unroll
      for (int r = 0; r < 4; ++r) {
        const int nl = i * 16 + quad * 4 + r;
        outp[nl * FT + ft] = acc[i][q][r] * rcpZ[nl];
      }
    }
  }
}

// block 256 thr, grid (512, 8): 4 n's per block; thread = (nl = t>>6, o = t&63)
__global__ __launch_bounds__(256) void k_out(
    const float* __restrict__ x, const float* __restrict__ Theta,
    const float* __restrict__ coef0, const float* __restrict__ rhs,
    float* __restrict__ out) {
  __shared__ float xs[4][FT], r1s[4][FT], r2s[4][FT];
  const int b = blockIdx.y, n0 = blockIdx.x * 4;
  const int t = threadIdx.x, o = t & 63, nl = t >> 6;
  const float* xsrc = x + ((size_t)b * NN + n0) * FT;
  const float* r1src = rhs + ((size_t)(b * 2 + 0) * NN + n0) * FT;
  const float* r2src = rhs + ((size_t)(b * 2 + 1) * NN + n0) * FT;
#pragma unroll
  for (int p = 0; p < 3; ++p) {
    const int idx = t + p * 256;  // 0..767
    const int rr = idx / FT, cc = idx % FT;
    xs[rr][cc] = xsrc[idx];
    r1s[rr][cc] = r1src[idx];
    r2s[rr][cc] = r2src[idx];
  }
  __syncthreads();
  const float c0 = coef0[b * NN + n0 + nl];
  float a[12];
#pragma unroll
  for (int tt = 0; tt < 12; ++tt) a[tt] = 0.f;
#pragma unroll
  for (int f = 0; f < 16; ++f) {
    const float th0 = Theta[(0 * 16 + f) * 64 + o] * c0;
    const float th1 = Theta[(1 * 16 + f) * 64 + o];
    const float th2 = Theta[(2 * 16 + f) * 64 + o];
#pragma unroll
    for (int tt = 0; tt < 12; ++tt) {
      a[tt] += th0 * xs[nl][f * 12 + tt] + th1 * r1s[nl][f * 12 + tt] +
               th2 * r2s[nl][f * 12 + tt];
    }
  }
  float* op = out + (((size_t)b * NN + n0 + nl) * 64 + o) * 12;
#pragma unroll
  for (int tt = 0; tt < 12; ++tt) a[tt] = fmaxf(a[tt], 0.f);
  float4* op4 = (float4*)op;
  op4[0] = make_float4(a[0], a[1], a[2], a[3]);
  op4[1] = make_float4(a[4], a[5], a[6], a[7]);
  op4[2] = make_float4(a[8], a[9], a[10], a[11]);
}

extern "C" void kernel_launch(void* const* d_in, const int* in_sizes, int n_in,
                              void* d_out, int out_size, void* d_ws, size_t ws_size,
                              hipStream_t stream) {
  const float* x = (const float*)d_in[0];
  const float* s_attn = (const float*)d_in[1];
  const float* adj = (const float*)d_in[2];
  const float* Theta = (const float*)d_in[3];
  float* out = (float*)d_out;
  char* ws = (char*)d_ws;

  // ws layout (bytes):
  //   xT   : [0, 6291456)            (8*192*2048 bf16)
  //   deg  : [6291456, 6299648)      (2048 f32)
  //   coef0: [6299648, 6365184)      (8*2048 f32)
  //   rhs  : [6365184, 31531008)     (16*2048*192 f32)
  if (ws_size < 31531008u) return;
  unsigned short* xT = (unsigned short*)ws;
  float* deg = (float*)(ws + 6291456);
  float* coef0 = (float*)(ws + 6299648);
  float* rhs = (float*)(ws + 6365184);

  hipLaunchKernelGGL(k_deg, dim3(NN), dim3(256), 0, stream, adj, deg);
  hipLaunchKernelGGL(k_xt, dim3(32, NB), dim3(256), 0, stream, x, xT);
  hipLaunchKernelGGL(k_main, dim3(32, NK, NB), dim3(192), 0, stream,
                     s_attn, adj, deg, xT, coef0, rhs);
  hipLaunchKernelGGL(k_out, dim3(512, NB), dim3(256), 0, stream,
                     x, Theta, coef0, rhs, out);
}

// Round 2
// 888.197 us; speedup vs baseline: 1.2054x; 1.2054x over previous
//
#include <hip/hip_runtime.h>

// cheb_conv_aagcn: B=8,K=3,N=2048,F_IN=16,F_OUT=64,T=12
// out[b,n,o,t] = relu( sum_k (1/Z_k[n]) sum_m exp(S[b,k,m,n]) cheb_k[m,n] x[b,m,:] @ Theta_k )
// cheb0=I (diagonal pick), cheb1=L=diag(deg)-adj, cheb2=2L*L-I (elementwise).
//
// k_deg : deg[n]
// k_xt  : xT[b][ft][m] bf16 (B-operand layout for MFMA, direct global loads)
// k_z0  : Z0 partials + diag exp for k=0 term
// k_main: k in {1,2}: split-m partial GEMM, fused exp/cheb -> bf16 Pt (LDS,
//         double-buffered, 1 barrier/chunk), B-frags direct from xT global.
//         Writes UNnormalized f32 partials + partial Z.
// k_out : combine partials, /Z, + k0 term, @Theta, relu.

#define NB 8
#define NN 2048
#define FT 192
#define BN 64
#define BM 64
#define LBM 72  // Pt row stride in bf16: 144B (16B-aligned)

typedef __attribute__((ext_vector_type(8))) short short8;
typedef __attribute__((ext_vector_type(4))) float f32x4;

__device__ __forceinline__ unsigned short bf16_rne(float f) {
  unsigned u = __float_as_uint(f);
  u += 0x7FFFu + ((u >> 16) & 1u);
  return (unsigned short)(u >> 16);
}

__global__ __launch_bounds__(256) void k_deg(const float* __restrict__ adj,
                                             float* __restrict__ deg) {
  const int row = blockIdx.x;
  const float* r = adj + (size_t)row * NN;
  float s = 0.f;
  for (int j = threadIdx.x; j < NN; j += 256) s += r[j];
  for (int off = 32; off; off >>= 1) s += __shfl_down(s, off, 64);
  __shared__ float ls[4];
  if ((threadIdx.x & 63) == 0) ls[threadIdx.x >> 6] = s;
  __syncthreads();
  if (threadIdx.x == 0) deg[row] = ls[0] + ls[1] + ls[2] + ls[3];
}

// grid (64, 8), block 192 (thread = ft). x[b][m][ft] -> xT[b][ft][m] bf16.
__global__ __launch_bounds__(192) void k_xt(const float* __restrict__ x,
                                            unsigned short* __restrict__ xT) {
  const int b = blockIdx.y, m0 = blockIdx.x * 32, ft = threadIdx.x;
  const float* src = x + (size_t)b * NN * FT + ft;
  uint4* dst = (uint4*)(xT + ((size_t)b * FT + ft) * NN + m0);
#pragma unroll
  for (int g = 0; g < 4; ++g) {
    unsigned u[4];
#pragma unroll
    for (int j = 0; j < 4; ++j) {
      float lo = src[(size_t)(m0 + g * 8 + 2 * j) * FT];
      float hi = src[(size_t)(m0 + g * 8 + 2 * j + 1) * FT];
      u[j] = (unsigned)bf16_rne(lo) | ((unsigned)bf16_rne(hi) << 16);
    }
    dst[g] = make_uint4(u[0], u[1], u[2], u[3]);
  }
}

// grid (32, 8, 4), block 256. Z0 partials over m-quarters + diag exp capture.
__global__ __launch_bounds__(256) void k_z0(const float* __restrict__ Sall,
                                            float* __restrict__ z0P,
                                            float* __restrict__ diagE) {
  __shared__ float zb[4][64];
  const int n0 = blockIdx.x * 64, b = blockIdx.y, msq = blockIdx.z;
  const int t = threadIdx.x, n = t & 63, mw = t >> 6;
  const float* S0 = Sall + (size_t)b * 3 * NN * NN;
  const int mstart = msq * 512 + mw * 128;
  const float* p = S0 + (size_t)mstart * NN + n0 + n;
  float z = 0.f;
#pragma unroll 4
  for (int i = 0; i < 128; ++i) {
    float e = __expf(p[(size_t)i * NN]);
    z += e;
    if (mstart + i == n0 + n) diagE[b * NN + n0 + n] = e;
  }
  zb[mw][n] = z;
  __syncthreads();
  if (t < 64) {
    float s = zb[0][t] + zb[1][t] + zb[2][t] + zb[3][t];
    z0P[((size_t)b * 4 + msq) * NN + n0 + t] = s;
  }
}

template <bool ISK1>
__device__ __forceinline__ void stage_pack(const float4 sv[8],
                                           const float* __restrict__ adj,
                                           const float* __restrict__ deg,
                                           int n0, int mb,
                                           unsigned short* __restrict__ buf,
                                           float zp[4], int n4, int mg) {
#pragma unroll
  for (int g = 0; g < 2; ++g) {
    float4 av[4];
    float dgv[4];
#pragma unroll
    for (int i = 0; i < 4; ++i) {
      const int m = mb + g * 4 + i;
      av[i] = *(const float4*)(adj + (size_t)m * NN + n0 + n4);
      dgv[i] = deg[m];
    }
    unsigned short pk[4][4];
#pragma unroll
    for (int i = 0; i < 4; ++i) {
      const int r = g * 4 + i, m = mb + r;
      const float se[4] = {sv[r].x, sv[r].y, sv[r].z, sv[r].w};
      const float ae[4] = {av[i].x, av[i].y, av[i].z, av[i].w};
#pragma unroll
      for (int j = 0; j < 4; ++j) {
        const bool diag = (m == n0 + n4 + j);
        const float e = __expf(se[j]);
        zp[j] += e;
        const float L = (diag ? dgv[i] : 0.f) - ae[j];
        const float cc = ISK1 ? L : (2.f * L * L - (diag ? 1.f : 0.f));
        pk[i][j] = bf16_rne(e * cc);
      }
    }
#pragma unroll
    for (int j = 0; j < 4; ++j) {
      uint2 v;
      v.x = (unsigned)pk[0][j] | ((unsigned)pk[1][j] << 16);
      v.y = (unsigned)pk[2][j] | ((unsigned)pk[3][j] << 16);
      *(uint2*)&buf[(n4 + j) * LBM + mg * 8 + g * 4] = v;
    }
  }
}

// grid (32, 2, 8*MS), block 192 (3 waves). kk: 0->cheb1, 1->cheb2.
template <int MS>
__global__ __launch_bounds__(192, 3) void k_main(
    const float* __restrict__ Sall, const float* __restrict__ adj,
    const float* __restrict__ deg, const unsigned short* __restrict__ xT,
    float* __restrict__ rhsP, float* __restrict__ z12P) {
  constexpr int C = 32 / MS;
  __shared__ unsigned short Pt[2][BN * LBM];
  __shared__ float Zred[8][BN];

  const int tile = blockIdx.x, kk = blockIdx.y;
  const int ms = blockIdx.z % MS, b = blockIdx.z / MS;
  const int n0 = tile * BN, mbase = ms * (C * BM);
  const int t = threadIdx.x, lane = t & 63, w = t >> 6;
  const int ln = lane & 15, quad = lane >> 4;
  const int n4 = (t & 15) * 4, mg = (t >> 4) & 7;
  const bool doPt = (t < 128);
  const float* S = Sall + (size_t)(b * 3 + 1 + kk) * NN * NN;

  const f32x4 zero4 = {0.f, 0.f, 0.f, 0.f};
  f32x4 acc[4][4];
#pragma unroll
  for (int i = 0; i < 4; ++i)
#pragma unroll
    for (int q = 0; q < 4; ++q) acc[i][q] = zero4;
  float zp[4] = {0.f, 0.f, 0.f, 0.f};

  // prologue: stage chunk 0 into buf 0
  if (doPt) {
    const int mb = mbase + mg * 8;
    float4 sv[8];
#pragma unroll
    for (int r = 0; r < 8; ++r)
      sv[r] = *(const float4*)(S + (size_t)(mb + r) * NN + n0 + n4);
    if (kk == 0)
      stage_pack<true>(sv, adj, deg, n0, mb, Pt[0], zp, n4, mg);
    else
      stage_pack<false>(sv, adj, deg, n0, mb, Pt[0], zp, n4, mg);
  }
  __syncthreads();

  for (int c = 0; c < C; ++c) {
    const int cur = c & 1;
    const bool more = (c + 1 < C);
    // prefetch next chunk's S early (hide HBM latency under MFMA)
    float4 sv[8];
    const int mbN = mbase + (c + 1) * BM + mg * 8;
    if (doPt && more) {
#pragma unroll
      for (int r = 0; r < 8; ++r)
        sv[r] = *(const float4*)(S + (size_t)(mbN + r) * NN + n0 + n4);
    }
    // B-frags direct from global xT (L2-hot)
    const int m0 = mbase + c * BM;
    short8 bfr[2][4];
#pragma unroll
    for (int ks2 = 0; ks2 < 2; ++ks2)
#pragma unroll
      for (int q = 0; q < 4; ++q)
        bfr[ks2][q] = *(const short8*)(xT +
            ((size_t)b * FT + (w * 4 + q) * 16 + ln) * NN + m0 + ks2 * 32 +
            quad * 8);
#pragma unroll
    for (int ks2 = 0; ks2 < 2; ++ks2) {
      short8 af[4];
#pragma unroll
      for (int i = 0; i < 4; ++i)
        af[i] = *(const short8*)&Pt[cur][(i * 16 + ln) * LBM + ks2 * 32 +
                                         quad * 8];
#pragma unroll
      for (int i = 0; i < 4; ++i)
#pragma unroll
        for (int q = 0; q < 4; ++q)
          acc[i][q] = __builtin_amdgcn_mfma_f32_16x16x32_bf16(
              af[i], bfr[ks2][q], acc[i][q], 0, 0, 0);
    }
    if (doPt && more) {
      if (kk == 0)
        stage_pack<true>(sv, adj, deg, n0, mbN, Pt[cur ^ 1], zp, n4, mg);
      else
        stage_pack<false>(sv, adj, deg, n0, mbN, Pt[cur ^ 1], zp, n4, mg);
    }
    __syncthreads();
  }

  if (doPt) {
#pragma unroll
    for (int j = 0; j < 4; ++j) Zred[mg][n4 + j] = zp[j];
  }
  __syncthreads();
  if (t < 64) {
    float Z = 0.f;
#pragma unroll
    for (int g = 0; g < 8; ++g) Z += Zred[g][t];
    z12P[((size_t)(kk * 8 + b) * MS + ms) * NN + n0 + t] = Z;
  }

  float* outp = rhsP + (((size_t)(kk * 8 + b) * MS + ms) * NN + n0) * FT;
#pragma unroll
  for (int i = 0; i < 4; ++i)
#pragma unroll
    for (int q = 0; q < 4; ++q) {
      const int ft = (w * 4 + q) * 16 + ln;
#pragma unroll
      for (int r = 0; r < 4; ++r) {
        const int nl = i * 16 + quad * 4 + r;
        outp[(size_t)nl * FT + ft] = acc[i][q][r];
      }
    }
}

// grid (512, 8), block 256: 4 n's per block, thread=(nl=t>>6, o=t&63)
__global__ __launch_bounds__(256) void k_out(
    const float* __restrict__ x, const float* __restrict__ Theta,
    const float* __restrict__ rhsP, const float* __restrict__ z12P,
    const float* __restrict__ z0P, const float* __restrict__ diagE,
    float* __restrict__ out, int MS) {
  __shared__ float xs[4][FT], r1s[4][FT], r2s[4][FT];
  __shared__ float sc[3][4];
  const int b = blockIdx.y, n0 = blockIdx.x * 4;
  const int t = threadIdx.x, o = t & 63, nl = t >> 6;

  for (int l = t; l < 576; l += 256) {
    const int arr = l / 192, idx = l - arr * 192;
    const int row = idx / 48, c4 = (idx % 48) * 4;
    if (arr == 0) {
      *(float4*)&xs[row][c4] =
          *(const float4*)(x + ((size_t)b * NN + n0 + row) * FT + c4);
    } else {
      float4 s = {0.f, 0.f, 0.f, 0.f};
      for (int ms = 0; ms < MS; ++ms) {
        const float4 v = *(const float4*)(rhsP +
            (((size_t)((arr - 1) * 8 + b) * MS + ms) * NN + n0 + row) * FT +
            c4);
        s.x += v.x; s.y += v.y; s.z += v.z; s.w += v.w;
      }
      float* dstbase = (arr == 1) ? &r1s[0][0] : &r2s[0][0];
      *(float4*)(dstbase + row * FT + c4) = s;
    }
  }
  if (t < 12) {
    const int j = t & 3, which = t >> 2;
    float v;
    if (which < 2) {
      float z = 0.f;
      for (int ms = 0; ms < MS; ++ms)
        z += z12P[((size_t)(which * 8 + b) * MS + ms) * NN + n0 + j];
      v = 1.f / z;
    } else {
      float z = 0.f;
      for (int q = 0; q < 4; ++q) z += z0P[((size_t)b * 4 + q) * NN + n0 + j];
      v = diagE[b * NN + n0 + j] / z;
    }
    sc[which][j] = v;
  }
  __syncthreads();

  float a0[12], a1[12], a2[12];
#pragma unroll
  for (int tt = 0; tt < 12; ++tt) a0[tt] = a1[tt] = a2[tt] = 0.f;
#pragma unroll
  for (int f = 0; f < 16; ++f) {
    const float th0 = Theta[(0 * 16 + f) * 64 + o];
    const float th1 = Theta[(1 * 16 + f) * 64 + o];
    const float th2 = Theta[(2 * 16 + f) * 64 + o];
#pragma unroll
    for (int tt = 0; tt < 12; ++tt) {
      a0[tt] += th0 * xs[nl][f * 12 + tt];
      a1[tt] += th1 * r1s[nl][f * 12 + tt];
      a2[tt] += th2 * r2s[nl][f * 12 + tt];
    }
  }
  const float rz1 = sc[0][nl], rz2 = sc[1][nl], c0 = sc[2][nl];
  float r[12];
#pragma unroll
  for (int tt = 0; tt < 12; ++tt)
    r[tt] = fmaxf(a0[tt] * c0 + a1[tt] * rz1 + a2[tt] * rz2, 0.f);
  float4* op4 = (float4*)(out + (((size_t)b * NN + n0 + nl) * 64 + o) * 12);
  op4[0] = make_float4(r[0], r[1], r[2], r[3]);
  op4[1] = make_float4(r[4], r[5], r[6], r[7]);
  op4[2] = make_float4(r[8], r[9], r[10], r[11]);
}

extern "C" void kernel_launch(void* const* d_in, const int* in_sizes, int n_in,
                              void* d_out, int out_size, void* d_ws,
                              size_t ws_size, hipStream_t stream) {
  const float* x = (const float*)d_in[0];
  const float* s_attn = (const float*)d_in[1];
  const float* adj = (const float*)d_in[2];
  const float* Theta = (const float*)d_in[3];
  float* out = (float*)d_out;
  char* ws = (char*)d_ws;

  const size_t szXT = (size_t)NB * FT * NN * 2;       // 6,291,456
  const size_t szDeg = NN * 4;                        // 8,192
  const size_t szZ0 = (size_t)NB * 4 * NN * 4;        // 262,144
  const size_t szDiag = (size_t)NB * NN * 4;          // 65,536
  const size_t base = szXT + szDeg + szZ0 + szDiag;
  const size_t perMS = (size_t)2 * NB * NN * 4        // z12P per split
                       + (size_t)2 * NB * NN * FT * 4;  // rhsP per split

  int MS = 0;
  if (ws_size >= base + 2 * perMS) MS = 2;
  else if (ws_size >= base + 1 * perMS) MS = 1;
  if (MS == 0) return;  // insufficient workspace

  unsigned short* xT = (unsigned short*)ws;
  float* deg = (float*)(ws + szXT);
  float* z0P = (float*)(ws + szXT + szDeg);
  float* diagE = (float*)(ws + szXT + szDeg + szZ0);
  float* z12P = (float*)(ws + base);
  float* rhsP = (float*)(ws + base + (size_t)2 * NB * MS * NN * 4);

  hipLaunchKernelGGL(k_deg, dim3(NN), dim3(256), 0, stream, adj, deg);
  hipLaunchKernelGGL(k_xt, dim3(64, NB), dim3(192), 0, stream, x, xT);
  hipLaunchKernelGGL(k_z0, dim3(32, NB, 4), dim3(256), 0, stream, s_attn, z0P,
                     diagE);
  if (MS == 2) {
    hipLaunchKernelGGL(k_main<2>, dim3(32, 2, NB * 2), dim3(192), 0, stream,
                       s_attn, adj, deg, xT, rhsP, z12P);
  } else {
    hipLaunchKernelGGL(k_main<1>, dim3(32, 2, NB * 1), dim3(192), 0, stream,
                       s_attn, adj, deg, xT, rhsP, z12P);
  }
  hipLaunchKernelGGL(k_out, dim3(512, NB), dim3(256), 0, stream, x, Theta,
                     rhsP, z12P, z0P, diagE, out, MS);
}